// Round 2
// baseline (82.957 us; speedup 1.0000x reference)
//
#include <hip/hip_runtime.h>
#include <cmath>

#define T_LEN 8192
#define B_ROWS 128
#define ND 360          // MAX_DELAY - MIN_DELAY
#define MIN_DELAY_C 60

// One wave (64 lanes) per batch row. No __syncthreads anywhere:
// all LDS dependencies are within a single wave, ordered by the
// compiler's lgkmcnt waits.
__global__ __launch_bounds__(64) void ks_resonator_kernel(
    const float* __restrict__ excitation,     // (128,1,8192)
    const float* __restrict__ gumbel,         // (360,)
    const float* __restrict__ delay_param,    // (360,)
    const float* __restrict__ feedback_gain,  // (1,)
    const float* __restrict__ refl,           // (2,)
    float* __restrict__ out)                  // (128,1,8192)
{
    __shared__ float y[T_LEN];   // 32 KB row buffer, in-place x -> y

    const int lane = threadIdx.x;   // 0..63
    const int row  = blockIdx.x;

    // ---- redundant per-wave argmax over (delay_param + gumbel), 360 elems ----
    float best = -INFINITY;
    int   bi   = 0;
    for (int i = lane; i < ND; i += 64) {
        float v = delay_param[i] + gumbel[i];
        if (v > best) { best = v; bi = i; }   // strictly-greater keeps first occurrence
    }
    // wave butterfly reduce (first-index wins ties)
    #pragma unroll
    for (int off = 32; off > 0; off >>= 1) {
        float v2 = __shfl_xor(best, off);
        int   i2 = __shfl_xor(bi, off);
        if (v2 > best || (v2 == best && i2 < bi)) { best = v2; bi = i2; }
    }
    const int p = bi;

    // ---- coefficients (redundant on every lane; all uniform) ----
    float k1 = tanhf(tanhf(refl[0]));
    float k2 = tanhf(tanhf(refl[1]));
    float a1 = k1 * (1.0f - k2);
    float a2 = fminf(fmaxf(k2, -0.999f), 0.999f);
    float bound = 0.999f - fabsf(a2);
    a1 = fminf(fmaxf(a1, -bound), bound);
    float g = powf(1.0f / (1.0f + expf(-feedback_gain[0])), 0.45f);
    a1 *= g; a2 *= g;

    const int lagA = MIN_DELAY_C + p + 1;             // tap delay of coeff at 60+p
    const int lagB = MIN_DELAY_C + ((p + 1) % ND) + 1;
    const int C    = (lagA < lagB) ? lagA : lagB;     // parallel-chunk width >= 61

    // ---- load row into LDS (float4, coalesced) ----
    const float4* xv = (const float4*)(excitation + (size_t)row * T_LEN);
    float4*       yv = (float4*)y;
    #pragma unroll 8
    for (int i = 0; i < T_LEN / 4 / 64; i++)
        yv[i * 64 + lane] = xv[i * 64 + lane];

    // ---- barrier-free chunked recurrence ----
    for (int pos = 0; pos < T_LEN; pos += C) {
        int end = pos + C; if (end > T_LEN) end = T_LEN;
        for (int j = pos + lane; j < end; j += 64) {
            float ya = (j >= lagA) ? y[j - lagA] : 0.0f;
            float yb = (j >= lagB) ? y[j - lagB] : 0.0f;
            y[j] = y[j] - a1 * ya - a2 * yb;
        }
    }

    // ---- store (float4, coalesced) ----
    float4* ov = (float4*)(out + (size_t)row * T_LEN);
    #pragma unroll 8
    for (int i = 0; i < T_LEN / 4 / 64; i++)
        ov[i * 64 + lane] = yv[i * 64 + lane];
}

extern "C" void kernel_launch(void* const* d_in, const int* in_sizes, int n_in,
                              void* d_out, int out_size, void* d_ws, size_t ws_size,
                              hipStream_t stream) {
    const float* excitation    = (const float*)d_in[0];
    const float* gumbel        = (const float*)d_in[1];
    const float* delay_param   = (const float*)d_in[2];
    const float* feedback_gain = (const float*)d_in[3];
    const float* refl          = (const float*)d_in[4];
    float* out = (float*)d_out;

    ks_resonator_kernel<<<B_ROWS, 64, 0, stream>>>(
        excitation, gumbel, delay_param, feedback_gain, refl, out);
}